// Round 1
// baseline (332.089 us; speedup 1.0000x reference)
//
#include <hip/hip_runtime.h>
#include <stdint.h>

#define SEQ 2048
#define DM  2048
#define NH  32
#define HDIM 64

typedef unsigned short u16;
typedef short bf16x8 __attribute__((ext_vector_type(8)));
typedef float f32x4 __attribute__((ext_vector_type(4)));

__device__ __forceinline__ u16 f2bf(float f) {
    union { float f; uint32_t u; } v; v.f = f;
    uint32_t u = v.u;
    uint32_t r = (u + 0x7fffu + ((u >> 16) & 1u)) >> 16;
    return (u16)r;
}

// ---------------- fp32 -> bf16 conversion of X, Wq, Wk, Wv, Wo ----------------
__global__ __launch_bounds__(256) void convert_bf16(
    const float* __restrict__ X, const float* __restrict__ Wq,
    const float* __restrict__ Wk, const float* __restrict__ Wv,
    const float* __restrict__ Wo,
    u16* __restrict__ Xb, u16* __restrict__ Wqb, u16* __restrict__ Wkb,
    u16* __restrict__ Wvb, u16* __restrict__ Wob)
{
    const int NV = (DM * SEQ) / 4;   // float4 count per 2048x2048 array
    int idx = blockIdx.x * blockDim.x + threadIdx.x;
    int total = NV * 5;
    for (; idx < total; idx += gridDim.x * blockDim.x) {
        int arr = idx / NV, i = idx - arr * NV;
        const float4* s; u16* d;
        switch (arr) {
            case 0:  s = (const float4*)X;  d = Xb;  break;
            case 1:  s = (const float4*)Wq; d = Wqb; break;
            case 2:  s = (const float4*)Wk; d = Wkb; break;
            case 3:  s = (const float4*)Wv; d = Wvb; break;
            default: s = (const float4*)Wo; d = Wob; break;
        }
        float4 v = s[i];
        ushort4 o;
        o.x = f2bf(v.x); o.y = f2bf(v.y); o.z = f2bf(v.z); o.w = f2bf(v.w);
        *(ushort4*)(d + i * 4) = o;
    }
}

// ---------------- forget gates: f[h][s] = logsigmoid(x_s . Wf_h + bf_h) -------
__global__ __launch_bounds__(256) void gates_kernel(
    const float* __restrict__ X, const float* __restrict__ Wf,
    const float* __restrict__ bfp, float* __restrict__ F)
{
    int wid = (blockIdx.x * blockDim.x + threadIdx.x) >> 6;  // global wave id
    int lane = threadIdx.x & 63;
    int s = wid >> 5, h = wid & 31;
    const float4* x4 = (const float4*)(X + (size_t)s * DM);
    const float4* w4 = (const float4*)(Wf + (size_t)h * DM);
    float acc = 0.f;
#pragma unroll
    for (int i = 0; i < 8; i++) {
        float4 a = x4[i * 64 + lane], b = w4[i * 64 + lane];
        acc += a.x * b.x + a.y * b.y + a.z * b.z + a.w * b.w;
    }
#pragma unroll
    for (int m = 32; m >= 1; m >>= 1) acc += __shfl_xor(acc, m);
    if (lane == 0) {
        float g = acc + bfp[h];
        float f = fminf(g, 0.f) - log1pf(expf(-fabsf(g)));
        F[h * SEQ + s] = f;
    }
}

// ---------------- cumulative sum per head (in place), one wave per head -------
__global__ __launch_bounds__(64) void cumsum_kernel(float* __restrict__ F)
{
    int h = blockIdx.x;
    int lane = threadIdx.x;
    float off = 0.f;
    for (int c = 0; c < SEQ / 64; c++) {
        float v = F[h * SEQ + c * 64 + lane];
#pragma unroll
        for (int d = 1; d < 64; d <<= 1) {
            float t = __shfl_up(v, d);
            if (lane >= d) v += t;
        }
        F[h * SEQ + c * 64 + lane] = v + off;
        off += __shfl(v, 63);
    }
}

// ---------------- GEMM: C[m][n] = sum_k A[m][k] * B[n][k]  (x @ W^T) ----------
// 128x128 tile, BK=32, 4 waves each computing a 64x64 quadrant via 16x16x32 MFMA.
// LDS rows padded to 40 bf16 (80 B) -> b128 reads at the 4-lane/window floor.
template <bool STOREF32>
__global__ __launch_bounds__(256) void gemm_bt(
    const u16* __restrict__ A,
    const u16* __restrict__ B0, const u16* __restrict__ B1, const u16* __restrict__ B2,
    void* C0, void* C1, void* C2, int M, int N, int K)
{
    __shared__ u16 lA[128 * 40];
    __shared__ u16 lB[128 * 40];
    int z = blockIdx.z;
    const u16* Bm = (z == 0) ? B0 : ((z == 1) ? B1 : B2);
    void* Cm = (z == 0) ? C0 : ((z == 1) ? C1 : C2);
    int m0 = blockIdx.y * 128, n0 = blockIdx.x * 128;
    int tid = threadIdx.x;
    int wave = tid >> 6, lane = tid & 63, ln = lane & 15, quad = lane >> 4;
    int wr = (wave >> 1) * 64, wc = (wave & 1) * 64;

    f32x4 acc[4][4];
#pragma unroll
    for (int i = 0; i < 4; i++)
#pragma unroll
        for (int j = 0; j < 4; j++)
#pragma unroll
            for (int r = 0; r < 4; r++) acc[i][j][r] = 0.f;

    int srow = tid >> 2, sseg = tid & 3;   // staging: 64 rows x 4 segs of 16B
    for (int k0 = 0; k0 < K; k0 += 32) {
        __syncthreads();
        *(uint4*)(&lA[srow * 40 + sseg * 8])        = *(const uint4*)(&A[(size_t)(m0 + srow) * K + k0 + sseg * 8]);
        *(uint4*)(&lA[(srow + 64) * 40 + sseg * 8]) = *(const uint4*)(&A[(size_t)(m0 + srow + 64) * K + k0 + sseg * 8]);
        *(uint4*)(&lB[srow * 40 + sseg * 8])        = *(const uint4*)(&Bm[(size_t)(n0 + srow) * K + k0 + sseg * 8]);
        *(uint4*)(&lB[(srow + 64) * 40 + sseg * 8]) = *(const uint4*)(&Bm[(size_t)(n0 + srow + 64) * K + k0 + sseg * 8]);
        __syncthreads();
        bf16x8 af[4], bfr[4];
#pragma unroll
        for (int i = 0; i < 4; i++) af[i]  = *(const bf16x8*)(&lA[(wr + i * 16 + ln) * 40 + quad * 8]);
#pragma unroll
        for (int j = 0; j < 4; j++) bfr[j] = *(const bf16x8*)(&lB[(wc + j * 16 + ln) * 40 + quad * 8]);
#pragma unroll
        for (int i = 0; i < 4; i++)
#pragma unroll
            for (int j = 0; j < 4; j++)
                acc[i][j] = __builtin_amdgcn_mfma_f32_16x16x32_bf16(af[i], bfr[j], acc[i][j], 0, 0, 0);
    }

    // epilogue: C row = quad*4 + reg, col = lane&15 (verified m89/m91 layout)
#pragma unroll
    for (int i = 0; i < 4; i++) {
#pragma unroll
        for (int j = 0; j < 4; j++) {
#pragma unroll
            for (int r = 0; r < 4; r++) {
                int row = m0 + wr + i * 16 + quad * 4 + r;
                int col = n0 + wc + j * 16 + ln;
                float v = acc[i][j][r];
                if (STOREF32) ((float*)Cm)[(size_t)row * N + col] = v;
                else          ((u16*)Cm)[(size_t)row * N + col]   = f2bf(v);
            }
        }
    }
}

// ---------------- flash attention with forget-gate decay ----------------------
// Block = 4 waves; block handles (head h, 64 q-rows). Wave w owns q-rows
// [q0+16w, q0+16w+16). K/V staged per 64-row kv tile; decay-based tile skip.
__global__ __launch_bounds__(256) void attn_kernel(
    const u16* __restrict__ Q, const u16* __restrict__ K,
    const u16* __restrict__ V, const float* __restrict__ F,
    u16* __restrict__ O)
{
    __shared__ u16 lK[64 * 72];        // [kv][hd], rows padded to 72
    __shared__ u16 lV[64 * 72];        // transposed: [hd][kv], padded
    __shared__ u16 lP[4 * 16 * 72];    // per-wave 16x64 P strip, padded
    __shared__ float lFq[64];
    __shared__ float lFk[64];

    int h = blockIdx.y;
    int q0 = blockIdx.x * 64;
    int tid = threadIdx.x;
    int wave = tid >> 6, lane = tid & 63, ln = lane & 15, quad = lane >> 4;
    const float scale = 0.125f;        // HD^-0.5

    // Q fragments (A-operand layout: m = lane&15, k = quad*8 + j)
    bf16x8 aq[2];
    int qrow = q0 + wave * 16 + ln;
#pragma unroll
    for (int kk = 0; kk < 2; kk++)
        aq[kk] = *(const bf16x8*)(&Q[(size_t)qrow * DM + h * HDIM + kk * 32 + quad * 8]);

    if (tid < 64) lFq[tid] = F[h * SEQ + q0 + tid];

    float m_run[4], l_run[4];
    f32x4 o_acc[4];
#pragma unroll
    for (int r = 0; r < 4; r++) { m_run[r] = -1e30f; l_run[r] = 0.f; }
#pragma unroll
    for (int jo = 0; jo < 4; jo++)
#pragma unroll
        for (int r = 0; r < 4; r++) o_acc[jo][r] = 0.f;

    float Fq0 = F[h * SEQ + q0];
    int nt = q0 / 64 + 1;
    u16* lPw = &lP[wave * 16 * 72];

    for (int kt = 0; kt < nt; kt++) {
        int kb = kt * 64;
        if (kt < nt - 1) {
            // max bias over tile pair = F[q0] - F[kb+63] (F non-increasing).
            // residual contribution < e^-35 -> negligible vs 5.6e-2 threshold.
            float Fkend = F[h * SEQ + kb + 63];
            if (Fq0 - Fkend < -50.f) continue;   // uniform across block
        }
        __syncthreads();   // previous tile fully consumed
        {   // stage K tile [64][64] (rows 0..31 and 32..63)
            int row = tid >> 3, seg = tid & 7;
            *(uint4*)(&lK[row * 72 + seg * 8])        = *(const uint4*)(&K[(size_t)(kb + row) * DM + h * HDIM + seg * 8]);
            *(uint4*)(&lK[(row + 32) * 72 + seg * 8]) = *(const uint4*)(&K[(size_t)(kb + row + 32) * DM + h * HDIM + seg * 8]);
        }
        // stage V transposed: lV[hd][kv]
#pragma unroll
        for (int half = 0; half < 2; half++) {
            int job = half * 256 + tid;
            int kv = job & 63, hs = job >> 6;
            union { uint4 v; u16 e[8]; } tmp;
            tmp.v = *(const uint4*)(&V[(size_t)(kb + kv) * DM + h * HDIM + hs * 8]);
#pragma unroll
            for (int u = 0; u < 8; u++) lV[(hs * 8 + u) * 72 + kv] = tmp.e[u];
        }
        if (tid < 64) lFk[tid] = F[h * SEQ + kb + tid];
        __syncthreads();

        // S = Q_strip @ K_tile^T
        f32x4 s_acc[4];
#pragma unroll
        for (int j = 0; j < 4; j++)
#pragma unroll
            for (int r = 0; r < 4; r++) s_acc[j][r] = 0.f;
#pragma unroll
        for (int kk = 0; kk < 2; kk++)
#pragma unroll
            for (int j = 0; j < 4; j++) {
                bf16x8 bk = *(const bf16x8*)(&lK[(j * 16 + ln) * 72 + kk * 32 + quad * 8]);
                s_acc[j] = __builtin_amdgcn_mfma_f32_16x16x32_bf16(aq[kk], bk, s_acc[j], 0, 0, 0);
            }

        bool diag = (kt == nt - 1);
        int qbase = q0 + wave * 16 + quad * 4;
        float vv[4][4];    // [j][r]
        float m_new[4];
#pragma unroll
        for (int r = 0; r < 4; r++) m_new[r] = -1e30f;
#pragma unroll
        for (int j = 0; j < 4; j++) {
            float fk = lFk[j * 16 + ln];
            int kglob = kb + j * 16 + ln;
#pragma unroll
            for (int r = 0; r < 4; r++) {
                float fq = lFq[wave * 16 + quad * 4 + r];
                float v = s_acc[j][r] * scale + (fq - fk);
                if (diag && kglob > qbase + r) v = -1e30f;
                vv[j][r] = v;
                m_new[r] = fmaxf(m_new[r], v);
            }
        }
        // row-wise max: reduce across the 16 lanes of this quad
#pragma unroll
        for (int r = 0; r < 4; r++) {
#pragma unroll
            for (int m = 1; m < 16; m <<= 1) m_new[r] = fmaxf(m_new[r], __shfl_xor(m_new[r], m));
        }
        float alpha[4];
#pragma unroll
        for (int r = 0; r < 4; r++) {
            float mt = fmaxf(m_run[r], m_new[r]);
            alpha[r] = expf(m_run[r] - mt);
            m_run[r] = mt;
        }
        float lsum[4] = {0.f, 0.f, 0.f, 0.f};
#pragma unroll
        for (int j = 0; j < 4; j++)
#pragma unroll
            for (int r = 0; r < 4; r++) {
                float pv = expf(vv[j][r] - m_run[r]);
                vv[j][r] = pv;
                lsum[r] += pv;
            }
#pragma unroll
        for (int r = 0; r < 4; r++) {
#pragma unroll
            for (int m = 1; m < 16; m <<= 1) lsum[r] += __shfl_xor(lsum[r], m);
            l_run[r] = l_run[r] * alpha[r] + lsum[r];
        }
#pragma unroll
        for (int jo = 0; jo < 4; jo++)
#pragma unroll
            for (int r = 0; r < 4; r++) o_acc[jo][r] *= alpha[r];

        // P: C-layout -> LDS -> A-layout (cross-lane: needs a real barrier)
#pragma unroll
        for (int j = 0; j < 4; j++)
#pragma unroll
            for (int r = 0; r < 4; r++)
                lPw[(quad * 4 + r) * 72 + j * 16 + ln] = f2bf(vv[j][r]);
        __syncthreads();
        bf16x8 ap[2];
#pragma unroll
        for (int kk = 0; kk < 2; kk++)
            ap[kk] = *(const bf16x8*)(&lPw[ln * 72 + kk * 32 + quad * 8]);
        // O_strip += P @ V_tile
#pragma unroll
        for (int kk = 0; kk < 2; kk++)
#pragma unroll
            for (int jo = 0; jo < 4; jo++) {
                bf16x8 bv = *(const bf16x8*)(&lV[(jo * 16 + ln) * 72 + kk * 32 + quad * 8]);
                o_acc[jo] = __builtin_amdgcn_mfma_f32_16x16x32_bf16(ap[kk], bv, o_acc[jo], 0, 0, 0);
            }
    }

    // epilogue: normalize and store bf16 O
#pragma unroll
    for (int r = 0; r < 4; r++) {
        float inv = 1.f / l_run[r];
        int row = q0 + wave * 16 + quad * 4 + r;
#pragma unroll
        for (int jo = 0; jo < 4; jo++)
            O[(size_t)row * DM + h * HDIM + jo * 16 + ln] = f2bf(o_acc[jo][r] * inv);
    }
}

// ------------------------------------------------------------------------------
extern "C" void kernel_launch(void* const* d_in, const int* in_sizes, int n_in,
                              void* d_out, int out_size, void* d_ws, size_t ws_size,
                              hipStream_t stream)
{
    const float* X   = (const float*)d_in[0];
    const float* Wq  = (const float*)d_in[1];
    const float* Wk  = (const float*)d_in[2];
    const float* Wv  = (const float*)d_in[3];
    const float* Wf  = (const float*)d_in[4];
    const float* bfp = (const float*)d_in[5];
    const float* Wo  = (const float*)d_in[6];
    float* out = (float*)d_out;

    char* ws = (char*)d_ws;
    const size_t MB8 = (size_t)DM * SEQ * 2;  // 8 MiB per bf16 2048x2048
    u16* Xb  = (u16*)(ws + 0 * MB8);
    u16* Wqb = (u16*)(ws + 1 * MB8);
    u16* Wkb = (u16*)(ws + 2 * MB8);
    u16* Wvb = (u16*)(ws + 3 * MB8);
    u16* Wob = (u16*)(ws + 4 * MB8);
    u16* Qb  = (u16*)(ws + 5 * MB8);
    u16* Kb  = (u16*)(ws + 6 * MB8);
    u16* Vb  = (u16*)(ws + 7 * MB8);
    u16* Ob  = (u16*)(ws + 8 * MB8);
    float* Fb = (float*)(ws + 9 * MB8);       // 32*2048 fp32 = 256 KiB; total ~72.3 MiB

    convert_bf16<<<dim3(4096), dim3(256), 0, stream>>>(X, Wq, Wk, Wv, Wo, Xb, Wqb, Wkb, Wvb, Wob);
    gates_kernel<<<dim3(SEQ * NH / 4), dim3(256), 0, stream>>>(X, Wf, bfp, Fb);
    cumsum_kernel<<<dim3(NH), dim3(64), 0, stream>>>(Fb);
    gemm_bt<false><<<dim3(16, 16, 3), dim3(256), 0, stream>>>(
        Xb, Wqb, Wkb, Wvb, (void*)Qb, (void*)Kb, (void*)Vb, SEQ, DM, DM);
    attn_kernel<<<dim3(SEQ / 64, NH), dim3(256), 0, stream>>>(Qb, Kb, Vb, Fb, Ob);
    gemm_bt<true><<<dim3(16, 16, 1), dim3(256), 0, stream>>>(
        Ob, Wob, Wob, Wob, (void*)out, (void*)out, (void*)out, SEQ, DM, DM);
}